// Round 8
// baseline (227.404 us; speedup 1.0000x reference)
//
#include <hip/hip_runtime.h>

// NCA step collapsed: y = (w1*w0) applied to depthwise-perception == single
// 8->8 channel 3x3 circular conv with folded kernel K[c][c'][3][3].
// out = clamp(grid + (noise<0.5) * conv(grid, K), 0, 1)
//
// v8 = v1 (re-validated anchor, 114 us) + two v2-validated reorderings:
//  1. staging index math: incremental advance (col+=58,r+=3, carry at 66/18)
//     instead of per-iteration magic-multiply divides  [pattern passed in v2]
//  2. noise prefetched into 32 registers before __syncthreads so epilogue
//     global-load latency drains under the staging barrier (VGPR ~90, still
//     LDS-bound occupancy, so free)

#define B_ 16
#define C_ 8
#define H_ 512
#define W_ 512
#define HID_ 32
#define F_ 5

#define TH 16
#define TW 64

// ---- prep: fold w1 @ w0 @ filters into K[8][8][9] ----
__global__ void nca_prep(const float* __restrict__ filters,  // [5][3][3]
                         const float* __restrict__ w0,       // [32][40]
                         const float* __restrict__ w1,       // [8][32]
                         float* __restrict__ K)               // [8][8][9]
{
    int idx = blockIdx.x * blockDim.x + threadIdx.x;
    if (idx >= C_ * C_ * 9) return;
    int k  = idx % 9;
    int t  = idx / 9;
    int cp = t % C_;   // input channel
    int c  = t / C_;   // output channel
    float acc = 0.f;
    #pragma unroll
    for (int f = 0; f < F_; ++f) {
        float we = 0.f;
        for (int o = 0; o < HID_; ++o)
            we += w1[c * HID_ + o] * w0[o * (C_ * F_) + cp * F_ + f];
        acc += we * filters[f * 9 + k];
    }
    K[idx] = acc;
}

// ---- main: tiled fused conv + mask + residual + clamp ----
__global__ __launch_bounds__(256) void nca_main(
    const float* __restrict__ grid,
    const float* __restrict__ noise,
    const float* __restrict__ K,      // [8][8][9]
    float* __restrict__ out)
{
    __shared__ float lds[C_][TH + 2][TW + 2];   // 8*18*66*4 = 38016 B

    const int b  = blockIdx.z;
    const int h0 = blockIdx.y * TH;
    const int w0 = blockIdx.x * TW;
    const int tid = threadIdx.x;

    const int lw  = tid & 63;          // 0..63 -> column in tile
    const int lh0 = (tid >> 6) << 2;   // 0,4,8,12 -> base row of 4-row strip

    // stage 8 channels with 1-px circular halo.
    // Incremental (c,r,col) advance: stride 256 = 3 rows + 58 cols in a
    // 66-wide row, carry thresholds 66 (row) / 18 (channel). [v2-validated]
    const int PER_CH = (TH + 2) * (TW + 2);       // 1188
    const int TOTAL  = C_ * PER_CH;               // 9504
    {
        int sr   = tid / 66;                      // 0..3 (one-time divide)
        int scol = tid - sr * 66;
        int sc   = 0;
        for (int i = tid; i < TOTAL; i += 256) {
            const int gh = (h0 + sr - 1) & (H_ - 1);
            const int gw = (w0 + scol - 1) & (W_ - 1);
            (&lds[0][0][0])[i] = grid[(((b << 3) + sc) << 18) + (gh << 9) + gw];
            scol += 58; sr += 3;
            if (scol >= 66) { scol -= 66; ++sr; }
            if (sr >= 18)   { sr -= 18; ++sc; }
        }
    }

    // noise prefetch: 32 independent loads issued before the barrier; their
    // latency drains while the slowest staging wave finishes
    float nz[C_][4];
    #pragma unroll
    for (int c = 0; c < C_; ++c)
        #pragma unroll
        for (int p = 0; p < 4; ++p)
            nz[c][p] = noise[(((b << 3) + c) << 18) +
                             ((h0 + lh0 + p) << 9) + (w0 + lw)];

    __syncthreads();

    float acc[C_][4];
    #pragma unroll
    for (int c = 0; c < C_; ++c)
        #pragma unroll
        for (int p = 0; p < 4; ++p) acc[c][p] = 0.f;

    for (int cp = 0; cp < C_; ++cp) {
        float v[6][3];
        #pragma unroll
        for (int r = 0; r < 6; ++r)
            #pragma unroll
            for (int cc = 0; cc < 3; ++cc)
                v[r][cc] = lds[cp][lh0 + r][lw + cc];

        #pragma unroll
        for (int c = 0; c < C_; ++c) {
            #pragma unroll
            for (int kh = 0; kh < 3; ++kh) {
                #pragma unroll
                for (int kw = 0; kw < 3; ++kw) {
                    const float kv = K[(c * C_ + cp) * 9 + kh * 3 + kw];
                    #pragma unroll
                    for (int p = 0; p < 4; ++p)
                        acc[c][p] += kv * v[p + kh][kw];
                }
            }
        }
    }

    // epilogue: mask, residual, clamp, store
    #pragma unroll
    for (int c = 0; c < C_; ++c) {
        #pragma unroll
        for (int p = 0; p < 4; ++p) {
            const int h  = h0 + lh0 + p;
            const int gi = (((b << 3) + c) << 18) + (h << 9) + (w0 + lw);
            const float g = lds[c][lh0 + p + 1][lw + 1];
            const float m = (nz[c][p] < 0.5f) ? 1.0f : 0.0f;
            float nv = g + acc[c][p] * m;
            nv = fminf(fmaxf(nv, 0.0f), 1.0f);
            out[gi] = nv;
        }
    }
}

extern "C" void kernel_launch(void* const* d_in, const int* in_sizes, int n_in,
                              void* d_out, int out_size, void* d_ws, size_t ws_size,
                              hipStream_t stream)
{
    const float* grid    = (const float*)d_in[0];
    const float* noise   = (const float*)d_in[1];
    const float* filters = (const float*)d_in[2];
    const float* w0      = (const float*)d_in[3];
    const float* w1      = (const float*)d_in[4];
    float* out = (float*)d_out;
    float* K   = (float*)d_ws;   // 576 floats

    nca_prep<<<1, 576, 0, stream>>>(filters, w0, w1, K);

    dim3 g(W_ / TW, H_ / TH, B_);
    nca_main<<<g, 256, 0, stream>>>(grid, noise, K, out);
}

// Round 9
// 131.350 us; speedup vs baseline: 1.7313x; 1.7313x over previous
//
#include <hip/hip_runtime.h>

// NCA step collapsed: y = (w1*w0) applied to depthwise-perception == single
// 8->8 channel 3x3 circular conv with folded kernel K[c][c'][3][3].
// out = clamp(grid + (noise<0.5) * conv(grid, K), 0, 1)
//
// v9 = v1 skeleton EXACTLY (independent-iteration staging with divides,
// same compute loops, same epilogue/stores, 32 outputs/thread) with ONE
// isolated change: LDS tile stored as bf16 (values in [0,1), RNE convert)
// -> LDS 38.4KB -> 19.0KB -> 8 blocks/CU residency headroom.
// Lesson from v2/v8: staging iterations must stay independent (no carry
// chains); no load prefetch across the barrier (vmcnt queue pressure).

#define B_ 16
#define C_ 8
#define H_ 512
#define W_ 512
#define HID_ 32
#define F_ 5

#define TH 16
#define TW 64
#define ROWS (TH + 2)              // 18
#define RW 66                      // LDS row width
#define PER_CH (ROWS * RW)         // 1188
#define TOTAL (C_ * PER_CH)        // 9504

// ---- prep: fold w1 @ w0 @ filters into K[8][8][9] ----
__global__ void nca_prep(const float* __restrict__ filters,  // [5][3][3]
                         const float* __restrict__ w0,       // [32][40]
                         const float* __restrict__ w1,       // [8][32]
                         float* __restrict__ K)               // [8][8][9]
{
    int idx = blockIdx.x * blockDim.x + threadIdx.x;
    if (idx >= C_ * C_ * 9) return;
    int k  = idx % 9;
    int t  = idx / 9;
    int cp = t % C_;   // input channel
    int c  = t / C_;   // output channel
    float acc = 0.f;
    #pragma unroll
    for (int f = 0; f < F_; ++f) {
        float we = 0.f;
        for (int o = 0; o < HID_; ++o)
            we += w1[c * HID_ + o] * w0[o * (C_ * F_) + cp * F_ + f];
        acc += we * filters[f * 9 + k];
    }
    K[idx] = acc;
}

__device__ __forceinline__ unsigned short f2bf(float f) {
    unsigned u = __builtin_bit_cast(unsigned, f);
    u += 0x7FFFu + ((u >> 16) & 1u);          // round-to-nearest-even
    return (unsigned short)(u >> 16);
}
__device__ __forceinline__ float bf2f(unsigned short s) {
    unsigned u = ((unsigned)s) << 16;
    return __builtin_bit_cast(float, u);
}

// ---- main: tiled fused conv + mask + residual + clamp ----
__global__ __launch_bounds__(256, 6) void nca_main(
    const float* __restrict__ grid,
    const float* __restrict__ noise,
    const float* __restrict__ K,      // [8][8][9]
    float* __restrict__ out)
{
    __shared__ unsigned short lds[TOTAL];   // 19008 B (bf16 tile)

    const int b  = blockIdx.z;
    const int h0 = blockIdx.y * TH;
    const int w0 = blockIdx.x * TW;
    const int tid = threadIdx.x;

    // stage 8 channels with 1-px circular halo (v1 pattern: each iteration's
    // index math is INDEPENDENT -> all loads pipeline in flight)
    for (int i = tid; i < TOTAL; i += 256) {
        int c   = i / PER_CH;
        int rem = i - c * PER_CH;
        int r   = rem / RW;
        int col = rem - r * RW;
        int gh  = (h0 + r - 1) & (H_ - 1);
        int gw  = (w0 + col - 1) & (W_ - 1);
        lds[i] = f2bf(grid[(((b << 3) + c) << 18) + (gh << 9) + gw]);
    }
    __syncthreads();

    const int lw  = tid & 63;          // 0..63 -> column in tile
    const int lh0 = (tid >> 6) << 2;   // 0,4,8,12 -> base row of 4-row strip

    float acc[C_][4];
    #pragma unroll
    for (int c = 0; c < C_; ++c)
        #pragma unroll
        for (int p = 0; p < 4; ++p) acc[c][p] = 0.f;

    for (int cp = 0; cp < C_; ++cp) {
        float v[6][3];
        #pragma unroll
        for (int r = 0; r < 6; ++r)
            #pragma unroll
            for (int cc = 0; cc < 3; ++cc)
                v[r][cc] = bf2f(lds[(cp * ROWS + lh0 + r) * RW + lw + cc]);

        #pragma unroll
        for (int c = 0; c < C_; ++c) {
            #pragma unroll
            for (int kh = 0; kh < 3; ++kh) {
                #pragma unroll
                for (int kw = 0; kw < 3; ++kw) {
                    const float kv = K[(c * C_ + cp) * 9 + kh * 3 + kw];
                    #pragma unroll
                    for (int p = 0; p < 4; ++p)
                        acc[c][p] += kv * v[p + kh][kw];
                }
            }
        }
    }

    // epilogue: mask, residual, clamp, store (v1 pattern)
    #pragma unroll
    for (int c = 0; c < C_; ++c) {
        #pragma unroll
        for (int p = 0; p < 4; ++p) {
            const int h  = h0 + lh0 + p;
            const int gi = (((b << 3) + c) << 18) + (h << 9) + (w0 + lw);
            const float g = bf2f(lds[(c * ROWS + lh0 + p + 1) * RW + lw + 1]);
            const float m = (noise[gi] < 0.5f) ? 1.0f : 0.0f;
            float nv = g + acc[c][p] * m;
            nv = fminf(fmaxf(nv, 0.0f), 1.0f);
            out[gi] = nv;
        }
    }
}

extern "C" void kernel_launch(void* const* d_in, const int* in_sizes, int n_in,
                              void* d_out, int out_size, void* d_ws, size_t ws_size,
                              hipStream_t stream)
{
    const float* grid    = (const float*)d_in[0];
    const float* noise   = (const float*)d_in[1];
    const float* filters = (const float*)d_in[2];
    const float* w0      = (const float*)d_in[3];
    const float* w1      = (const float*)d_in[4];
    float* out = (float*)d_out;
    float* K   = (float*)d_ws;   // 576 floats

    nca_prep<<<1, 576, 0, stream>>>(filters, w0, w1, K);

    dim3 g(W_ / TW, H_ / TH, B_);
    nca_main<<<g, 256, 0, stream>>>(grid, noise, K, out);
}